// Round 1
// baseline (682.732 us; speedup 1.0000x reference)
//
#include <hip/hip_runtime.h>
#include <hip/hip_bf16.h>
#include <stdint.h>

typedef __bf16 bf16x8 __attribute__((ext_vector_type(8)));
typedef float f32x4 __attribute__((ext_vector_type(4)));
typedef unsigned short ushort8 __attribute__((ext_vector_type(8)));

__device__ __forceinline__ unsigned short f2bf(float f) {
    unsigned int u = __builtin_bit_cast(unsigned int, f);
    u += 0x7fffu + ((u >> 16) & 1u);
    return (unsigned short)(u >> 16);
}

#define MFMA16(a, b, c) __builtin_amdgcn_mfma_f32_16x16x32_bf16( \
    __builtin_bit_cast(bf16x8, a), __builtin_bit_cast(bf16x8, b), c, 0, 0, 0)

// ---------------------------------------------------------------------------
// Kernel 1: qkv = x @ Wqkv + bqkv ; scatter bf16 into q/k/v [b,h,t,64]
// x: fp32 [8192,1024]  W: fp32 [1024,3072]  bias: fp32 [3072]
// ---------------------------------------------------------------------------
__global__ __launch_bounds__(256) void qkv_gemm(
    const float* __restrict__ x, const float* __restrict__ W,
    const float* __restrict__ bias, unsigned short* __restrict__ qkv)
{
    __shared__ __align__(16) unsigned short As[64][40];  // [m][k] bf16
    __shared__ __align__(16) unsigned short Bs[64][40];  // [n][k] bf16 (B^T)
    const int m0 = blockIdx.x * 64, n0 = blockIdx.y * 64;
    const int tid = threadIdx.x;
    const int lane = tid & 63, w = tid >> 6;
    const int lr = lane & 15, quad = lane >> 4;
    const int mh = (w & 1) * 32, nh = (w >> 1) * 32;
    f32x4 acc[2][2] = {};

    for (int k0 = 0; k0 < 1024; k0 += 32) {
        // stage A (fp32 -> bf16): 64 rows x 32 cols
        {
            int r = tid >> 2, c = (tid & 3) * 8;
            const float* src = x + (size_t)(m0 + r) * 1024 + k0 + c;
            float4 f0 = *(const float4*)src;
            float4 f1 = *(const float4*)(src + 4);
            ushort8 v;
            v[0]=f2bf(f0.x); v[1]=f2bf(f0.y); v[2]=f2bf(f0.z); v[3]=f2bf(f0.w);
            v[4]=f2bf(f1.x); v[5]=f2bf(f1.y); v[6]=f2bf(f1.z); v[7]=f2bf(f1.w);
            *(ushort8*)&As[r][c] = v;
        }
        // stage B transposed (fp32 -> bf16): W[k0+r][n0+c8..] -> Bs[c][r]
        {
            int r = tid >> 3, c8 = (tid & 7) * 8;
            const float* src = W + (size_t)(k0 + r) * 3072 + n0 + c8;
            float4 f0 = *(const float4*)src;
            float4 f1 = *(const float4*)(src + 4);
            float f[8] = {f0.x, f0.y, f0.z, f0.w, f1.x, f1.y, f1.z, f1.w};
            #pragma unroll
            for (int i = 0; i < 8; ++i) Bs[c8 + i][r] = f2bf(f[i]);
        }
        __syncthreads();
        ushort8 a0 = *(ushort8*)&As[mh + lr][quad * 8];
        ushort8 a1 = *(ushort8*)&As[mh + 16 + lr][quad * 8];
        ushort8 b0 = *(ushort8*)&Bs[nh + lr][quad * 8];
        ushort8 b1 = *(ushort8*)&Bs[nh + 16 + lr][quad * 8];
        acc[0][0] = MFMA16(a0, b0, acc[0][0]);
        acc[0][1] = MFMA16(a0, b1, acc[0][1]);
        acc[1][0] = MFMA16(a1, b0, acc[1][0]);
        acc[1][1] = MFMA16(a1, b1, acc[1][1]);
        __syncthreads();
    }

    // epilogue: add bias, scatter bf16 to [which][b,h,t,d]
    const int which = n0 >> 10;
    const int h = (n0 >> 6) & 15;
    float bv[2];
    bv[0] = bias[n0 + nh + lr];
    bv[1] = bias[n0 + nh + 16 + lr];
    unsigned short* dst_base = qkv + (size_t)which * 8388608;
    #pragma unroll
    for (int mt = 0; mt < 2; ++mt)
      #pragma unroll
      for (int nt = 0; nt < 2; ++nt)
        #pragma unroll
        for (int reg = 0; reg < 4; ++reg) {
            int row = mh + mt * 16 + quad * 4 + reg;
            int col = nh + nt * 16 + lr;
            int m = m0 + row;
            int b_idx = m >> 11, t_idx = m & 2047;
            int d = col;  // n0 is a multiple of 64
            float v = acc[mt][nt][reg] + bv[nt];
            dst_base[(((size_t)(b_idx * 16 + h) * 2048 + t_idx) << 6) + d] = f2bf(v);
        }
}

// ---------------------------------------------------------------------------
// Kernel 2: flash attention, one workgroup per (b, h, 64-row q-tile)
// qkv: bf16 [3][b,h,2048,64] ; o_ws: bf16 [b,2048,1024]
// ---------------------------------------------------------------------------
__global__ __launch_bounds__(256) void attn_kernel(
    const unsigned short* __restrict__ qkv, unsigned short* __restrict__ o_ws)
{
    const int qt = blockIdx.x;               // 0..31
    const int h = blockIdx.y, b = blockIdx.z;
    const unsigned short* Q = qkv + (size_t)(b * 16 + h) * 2048 * 64;
    const unsigned short* K = Q + 8388608;
    const unsigned short* V = Q + 2 * 8388608;
    __shared__ __align__(16) unsigned short Qs[64][72];   // [qrow][d]
    __shared__ __align__(16) unsigned short Ks[64][72];   // [krow][d]
    __shared__ __align__(16) unsigned short Vts[64][72];  // [d][krow]
    __shared__ __align__(16) unsigned short Ps[64][72];   // [qrow][krow]
    const int tid = threadIdx.x, lane = tid & 63, w = tid >> 6;
    const int lr = lane & 15, quad = lane >> 4;

    {
        int r = tid >> 2, c = (tid & 3) * 16;
        const unsigned short* src = Q + (size_t)(qt * 64 + r) * 64 + c;
        *(uint4*)&Qs[r][c]     = *(const uint4*)src;
        *(uint4*)&Qs[r][c + 8] = *(const uint4*)(src + 8);
    }
    float m_i[4], l_i[4];
    f32x4 o_acc[4] = {};
    #pragma unroll
    for (int r = 0; r < 4; ++r) { m_i[r] = -1e30f; l_i[r] = 0.f; }
    const float scale = 0.125f;  // 1/sqrt(64)

    for (int kt = 0; kt <= qt; ++kt) {
        __syncthreads();  // previous iter's reads of Ks/Vts/Ps done
        {
            int r = tid >> 2, c = (tid & 3) * 16;
            const unsigned short* ksrc = K + (size_t)(kt * 64 + r) * 64 + c;
            *(uint4*)&Ks[r][c]     = *(const uint4*)ksrc;
            *(uint4*)&Ks[r][c + 8] = *(const uint4*)(ksrc + 8);
            const unsigned short* vsrc = V + (size_t)(kt * 64 + r) * 64 + c;
            unsigned short tmp[16];
            *(uint4*)&tmp[0] = *(const uint4*)vsrc;
            *(uint4*)&tmp[8] = *(const uint4*)(vsrc + 8);
            #pragma unroll
            for (int i = 0; i < 16; ++i) Vts[c + i][r] = tmp[i];
        }
        __syncthreads();

        // S = Q K^T  (wave w owns q-rows [16w,16w+16))
        f32x4 s[4] = {};
        #pragma unroll
        for (int nt = 0; nt < 4; ++nt)
            #pragma unroll
            for (int kk = 0; kk < 2; ++kk) {
                ushort8 a  = *(ushort8*)&Qs[w * 16 + lr][kk * 32 + quad * 8];
                ushort8 bb = *(ushort8*)&Ks[nt * 16 + lr][kk * 32 + quad * 8];
                s[nt] = MFMA16(a, bb, s[nt]);
            }
        // scale + causal mask (diagonal tile only)
        #pragma unroll
        for (int nt = 0; nt < 4; ++nt)
            #pragma unroll
            for (int reg = 0; reg < 4; ++reg) {
                float sv = s[nt][reg] * scale;
                if (kt == qt) {
                    int qrow = w * 16 + quad * 4 + reg;
                    int kcol = nt * 16 + lr;
                    if (kcol > qrow) sv = -1e30f;
                }
                s[nt][reg] = sv;
            }
        // online softmax; row r of wave = 16w + quad*4 + reg, cols across 16 lanes
        float p[4][4], alpha[4];
        #pragma unroll
        for (int reg = 0; reg < 4; ++reg) {
            float mx = fmaxf(fmaxf(s[0][reg], s[1][reg]), fmaxf(s[2][reg], s[3][reg]));
            #pragma unroll
            for (int off = 1; off < 16; off <<= 1) mx = fmaxf(mx, __shfl_xor(mx, off, 64));
            float mnew = fmaxf(m_i[reg], mx);
            alpha[reg] = __expf(m_i[reg] - mnew);
            m_i[reg] = mnew;
            float rs = 0.f;
            #pragma unroll
            for (int nt = 0; nt < 4; ++nt) {
                float pv = __expf(s[nt][reg] - mnew);
                p[nt][reg] = pv;
                rs += pv;
            }
            #pragma unroll
            for (int off = 1; off < 16; off <<= 1) rs += __shfl_xor(rs, off, 64);
            l_i[reg] = l_i[reg] * alpha[reg] + rs;
        }
        #pragma unroll
        for (int dt = 0; dt < 4; ++dt)
            #pragma unroll
            for (int reg = 0; reg < 4; ++reg)
                o_acc[dt][reg] *= alpha[reg];
        // P: C-layout -> LDS (A-layout round trip)
        #pragma unroll
        for (int nt = 0; nt < 4; ++nt)
            #pragma unroll
            for (int reg = 0; reg < 4; ++reg)
                Ps[w * 16 + quad * 4 + reg][nt * 16 + lr] = f2bf(p[nt][reg]);
        __syncthreads();
        // O += P @ V
        #pragma unroll
        for (int dt = 0; dt < 4; ++dt)
            #pragma unroll
            for (int kk = 0; kk < 2; ++kk) {
                ushort8 a  = *(ushort8*)&Ps[w * 16 + lr][kk * 32 + quad * 8];
                ushort8 bb = *(ushort8*)&Vts[dt * 16 + lr][kk * 32 + quad * 8];
                o_acc[dt] = MFMA16(a, bb, o_acc[dt]);
            }
    }

    // epilogue: normalize, write bf16 [b, t, h*64 + d]
    #pragma unroll
    for (int dt = 0; dt < 4; ++dt)
        #pragma unroll
        for (int reg = 0; reg < 4; ++reg) {
            int row = w * 16 + quad * 4 + reg;
            int tq = qt * 64 + row;
            float ov = o_acc[dt][reg] / l_i[reg];
            o_ws[((size_t)(b * 2048 + tq) << 10) + h * 64 + dt * 16 + lr] = f2bf(ov);
        }
}

// ---------------------------------------------------------------------------
// Kernel 3: out = attn @ Wout + bout
// A: bf16 [8192,1024]  W: fp32 [1024,1024]  out: fp32 [8192,1024]
// ---------------------------------------------------------------------------
__global__ __launch_bounds__(256) void out_gemm(
    const unsigned short* __restrict__ A, const float* __restrict__ W,
    const float* __restrict__ bias, float* __restrict__ out)
{
    __shared__ __align__(16) unsigned short As[64][40];
    __shared__ __align__(16) unsigned short Bs[64][40];
    const int m0 = blockIdx.x * 64, n0 = blockIdx.y * 64;
    const int tid = threadIdx.x;
    const int lane = tid & 63, w = tid >> 6;
    const int lr = lane & 15, quad = lane >> 4;
    const int mh = (w & 1) * 32, nh = (w >> 1) * 32;
    f32x4 acc[2][2] = {};

    for (int k0 = 0; k0 < 1024; k0 += 32) {
        {
            int r = tid >> 2, c = (tid & 3) * 8;
            *(uint4*)&As[r][c] = *(const uint4*)(A + (size_t)(m0 + r) * 1024 + k0 + c);
        }
        {
            int r = tid >> 3, c8 = (tid & 7) * 8;
            const float* src = W + (size_t)(k0 + r) * 1024 + n0 + c8;
            float4 f0 = *(const float4*)src;
            float4 f1 = *(const float4*)(src + 4);
            float f[8] = {f0.x, f0.y, f0.z, f0.w, f1.x, f1.y, f1.z, f1.w};
            #pragma unroll
            for (int i = 0; i < 8; ++i) Bs[c8 + i][r] = f2bf(f[i]);
        }
        __syncthreads();
        ushort8 a0 = *(ushort8*)&As[mh + lr][quad * 8];
        ushort8 a1 = *(ushort8*)&As[mh + 16 + lr][quad * 8];
        ushort8 b0 = *(ushort8*)&Bs[nh + lr][quad * 8];
        ushort8 b1 = *(ushort8*)&Bs[nh + 16 + lr][quad * 8];
        acc[0][0] = MFMA16(a0, b0, acc[0][0]);
        acc[0][1] = MFMA16(a0, b1, acc[0][1]);
        acc[1][0] = MFMA16(a1, b0, acc[1][0]);
        acc[1][1] = MFMA16(a1, b1, acc[1][1]);
        __syncthreads();
    }

    float bv[2];
    bv[0] = bias[n0 + nh + lr];
    bv[1] = bias[n0 + nh + 16 + lr];
    #pragma unroll
    for (int mt = 0; mt < 2; ++mt)
      #pragma unroll
      for (int nt = 0; nt < 2; ++nt)
        #pragma unroll
        for (int reg = 0; reg < 4; ++reg) {
            int row = mh + mt * 16 + quad * 4 + reg;
            int col = nh + nt * 16 + lr;
            out[(size_t)(m0 + row) * 1024 + n0 + col] = acc[mt][nt][reg] + bv[nt];
        }
}

extern "C" void kernel_launch(void* const* d_in, const int* in_sizes, int n_in,
                              void* d_out, int out_size, void* d_ws, size_t ws_size,
                              hipStream_t stream)
{
    const float* x    = (const float*)d_in[0];
    const float* Wqkv = (const float*)d_in[1];
    const float* bqkv = (const float*)d_in[2];
    const float* Wout = (const float*)d_in[3];
    const float* bout = (const float*)d_in[4];
    float* out = (float*)d_out;

    // workspace: q/k/v bf16 [3][4,16,2048,64] then attn-out bf16 [4,2048,1024]
    unsigned short* qkv    = (unsigned short*)d_ws;          // 3 * 8388608 elems
    unsigned short* attn_o = qkv + (size_t)3 * 8388608;      // 8388608 elems

    qkv_gemm<<<dim3(128, 48), 256, 0, stream>>>(x, Wqkv, bqkv, qkv);
    attn_kernel<<<dim3(32, 16, 4), 256, 0, stream>>>(qkv, attn_o);
    out_gemm<<<dim3(128, 16), 256, 0, stream>>>(attn_o, Wout, bout, out);
}

// Round 2
// 397.964 us; speedup vs baseline: 1.7156x; 1.7156x over previous
//
#include <hip/hip_runtime.h>
#include <hip/hip_bf16.h>
#include <stdint.h>

typedef unsigned short u16;
typedef __bf16 bf16x8 __attribute__((ext_vector_type(8)));
typedef float f32x4 __attribute__((ext_vector_type(4)));
typedef u16 ushort8 __attribute__((ext_vector_type(8)));

__device__ __forceinline__ u16 f2bf(float f) {
    unsigned int u = __builtin_bit_cast(unsigned int, f);
    u += 0x7fffu + ((u >> 16) & 1u);
    return (u16)(u >> 16);
}

#define MFMA16(a, b, c) __builtin_amdgcn_mfma_f32_16x16x32_bf16( \
    __builtin_bit_cast(bf16x8, a), __builtin_bit_cast(bf16x8, b), c, 0, 0, 0)

// async global->LDS, 16B per lane. LDS dest = uniform base + lane*16.
__device__ __forceinline__ void async16(void* lds, const void* g) {
    __builtin_amdgcn_global_load_lds(
        (const __attribute__((address_space(1))) unsigned int*)(uintptr_t)g,
        (__attribute__((address_space(3))) unsigned int*)(unsigned int)(uintptr_t)lds,
        16, 0, 0);
}

// ---------------------------------------------------------------------------
// convert fp32 -> bf16, 8 elems/thread
// ---------------------------------------------------------------------------
__global__ __launch_bounds__(256) void convert_bf16(
    const float* __restrict__ src, u16* __restrict__ dst)
{
    int i = blockIdx.x * 256 + threadIdx.x;
    float4 f0 = ((const float4*)src)[i * 2];
    float4 f1 = ((const float4*)src)[i * 2 + 1];
    ushort8 v;
    v[0]=f2bf(f0.x); v[1]=f2bf(f0.y); v[2]=f2bf(f0.z); v[3]=f2bf(f0.w);
    v[4]=f2bf(f1.x); v[5]=f2bf(f1.y); v[6]=f2bf(f1.z); v[7]=f2bf(f1.w);
    ((ushort8*)dst)[i] = v;
}

// ---------------------------------------------------------------------------
// transpose+convert: src fp32 [K][N] -> dst bf16 [N][K]; 64x64 tiles
// ---------------------------------------------------------------------------
__global__ __launch_bounds__(256) void transpose_convert(
    const float* __restrict__ src, u16* __restrict__ dst, int N, int K)
{
    __shared__ u16 T[64][68];
    const int k0 = blockIdx.x * 64, n0 = blockIdx.y * 64;
    const int tid = threadIdx.x;
    const int rr = tid >> 4, cc = (tid & 15) * 4;
    #pragma unroll
    for (int rnd = 0; rnd < 4; ++rnd) {
        int r = rr + rnd * 16;
        float4 f = *(const float4*)&src[(size_t)(k0 + r) * N + n0 + cc];
        u16 v[4] = {f2bf(f.x), f2bf(f.y), f2bf(f.z), f2bf(f.w)};
        *(unsigned long long*)&T[r][cc] = *(unsigned long long*)v;
    }
    __syncthreads();
    #pragma unroll
    for (int rnd = 0; rnd < 4; ++rnd) {
        int rn = rr + rnd * 16;
        u16 v[4];
        #pragma unroll
        for (int j = 0; j < 4; ++j) v[j] = T[cc + j][rn];
        *(unsigned long long*)&dst[(size_t)(n0 + rn) * K + k0 + cc] =
            *(unsigned long long*)v;
    }
}

// ---------------------------------------------------------------------------
// shared 128x128 / BK=64 bf16 GEMM mainloop. A [M][1024], Bt [N][1024].
// LDS layout (swizzled for global_load_lds): [rowblk(16)][chunk(8)][row(8)][8]
// ---------------------------------------------------------------------------
__device__ __forceinline__ void gemm_mainloop(
    const u16* __restrict__ A, const u16* __restrict__ Bt,
    u16* As, u16* Bs, int m0, int n0, int tid, f32x4 acc[4][4])
{
    const int lane = tid & 63, w = tid >> 6;
    const int lr = lane & 15, quad = lane >> 4;
    const int wm = w & 1, wn = w >> 1;
    const int grow = lane & 7, gchunk = lane >> 3;

    for (int k0 = 0; k0 < 1024; k0 += 64) {
        __syncthreads();  // previous iter's frag reads done
        #pragma unroll
        for (int r = 0; r < 4; ++r) {
            int rb = w * 4 + r;
            async16(As + rb * 512,
                    A + (size_t)(m0 + rb * 8 + grow) * 1024 + k0 + gchunk * 8);
            async16(Bs + rb * 512,
                    Bt + (size_t)(n0 + rb * 8 + grow) * 1024 + k0 + gchunk * 8);
        }
        __syncthreads();  // drains vmcnt (async loads done)
        #pragma unroll
        for (int kk = 0; kk < 2; ++kk) {
            ushort8 a[4], b[4];
            #pragma unroll
            for (int mt = 0; mt < 4; ++mt) {
                int rb = wm * 8 + mt * 2 + (lr >> 3);
                a[mt] = *(ushort8*)&As[rb * 512 + (kk * 4 + quad) * 64 + (lr & 7) * 8];
            }
            #pragma unroll
            for (int nt = 0; nt < 4; ++nt) {
                int rb = wn * 8 + nt * 2 + (lr >> 3);
                b[nt] = *(ushort8*)&Bs[rb * 512 + (kk * 4 + quad) * 64 + (lr & 7) * 8];
            }
            #pragma unroll
            for (int mt = 0; mt < 4; ++mt)
                #pragma unroll
                for (int nt = 0; nt < 4; ++nt)
                    acc[mt][nt] = MFMA16(a[mt], b[nt], acc[mt][nt]);
        }
    }
}

// ---------------------------------------------------------------------------
// Kernel: qkv = xb @ WqkvT^T + bqkv ; scatter bf16 to q/k/v [b,h,t,64]
// ---------------------------------------------------------------------------
__global__ __launch_bounds__(256) void qkv_gemm(
    const u16* __restrict__ xb, const u16* __restrict__ Wt,
    const float* __restrict__ bias, u16* __restrict__ qkvb)
{
    __shared__ u16 As[8192], Bs[8192];
    const int m0 = blockIdx.x * 128, n0 = blockIdx.y * 128;
    const int tid = threadIdx.x;
    f32x4 acc[4][4] = {};
    gemm_mainloop(xb, Wt, As, Bs, m0, n0, tid, acc);

    const int lane = tid & 63, w = tid >> 6;
    const int lr = lane & 15, quad = lane >> 4;
    const int wm = w & 1, wn = w >> 1;
    float bv[4];
    #pragma unroll
    for (int nt = 0; nt < 4; ++nt) bv[nt] = bias[n0 + wn * 64 + nt * 16 + lr];
    #pragma unroll
    for (int mt = 0; mt < 4; ++mt)
      #pragma unroll
      for (int nt = 0; nt < 4; ++nt) {
        int n = n0 + wn * 64 + nt * 16 + lr;
        int which = n >> 10, hh = (n >> 6) & 15, d = n & 63;
        u16* dst = qkvb + (size_t)which * 8388608;
        #pragma unroll
        for (int reg = 0; reg < 4; ++reg) {
            int m = m0 + wm * 64 + mt * 16 + quad * 4 + reg;
            int b_idx = m >> 11, t_idx = m & 2047;
            dst[(((size_t)(b_idx * 16 + hh) * 2048 + t_idx) << 6) + d] =
                f2bf(acc[mt][nt][reg] + bv[nt]);
        }
      }
}

// ---------------------------------------------------------------------------
// Kernel: out = attn_o @ WoutT^T + bout (fp32 out)
// ---------------------------------------------------------------------------
__global__ __launch_bounds__(256) void out_gemm(
    const u16* __restrict__ A, const u16* __restrict__ Wt,
    const float* __restrict__ bias, float* __restrict__ out)
{
    __shared__ u16 As[8192], Bs[8192];
    const int m0 = blockIdx.x * 128, n0 = blockIdx.y * 128;
    const int tid = threadIdx.x;
    f32x4 acc[4][4] = {};
    gemm_mainloop(A, Wt, As, Bs, m0, n0, tid, acc);

    const int lane = tid & 63, w = tid >> 6;
    const int lr = lane & 15, quad = lane >> 4;
    const int wm = w & 1, wn = w >> 1;
    float bv[4];
    #pragma unroll
    for (int nt = 0; nt < 4; ++nt) bv[nt] = bias[n0 + wn * 64 + nt * 16 + lr];
    #pragma unroll
    for (int mt = 0; mt < 4; ++mt)
      #pragma unroll
      for (int nt = 0; nt < 4; ++nt)
        #pragma unroll
        for (int reg = 0; reg < 4; ++reg) {
            int m = m0 + wm * 64 + mt * 16 + quad * 4 + reg;
            int n = n0 + wn * 64 + nt * 16 + lr;
            out[(size_t)m * 1024 + n] = acc[mt][nt][reg] + bv[nt];
        }
}

// ---------------------------------------------------------------------------
// Flash attention. Grid (16 pairs, 16 h, 4 b); block = 256 = 4 waves.
// Block handles q-tiles p and 31-p -> exactly 33 kt-iterations (balanced).
// K async-staged (swizzled, conflict-free); V transpose-staged (b32+rotate);
// Q in registers; P via LDS round trip.
// ---------------------------------------------------------------------------
__global__ __launch_bounds__(256) void attn_kernel(
    const u16* __restrict__ qkvb, u16* __restrict__ o_ws)
{
    const int p = blockIdx.x, h = blockIdx.y, b = blockIdx.z;
    const u16* Q = qkvb + (size_t)(b * 16 + h) * 2048 * 64;
    const u16* K = Q + 8388608;
    const u16* V = Q + 2 * 8388608;
    __shared__ u16 Ks[4096];        // swizzled [rb(8)][chunk(8)][row(8)][8]
    __shared__ u16 Vts[64 * 72];    // [d][krow], pad 72
    __shared__ u16 Ps[64 * 72];     // [qrow][kcol], pad 72
    const int tid = threadIdx.x, lane = tid & 63, w = tid >> 6;
    const int lr = lane & 15, quad = lane >> 4;
    const int grow = lane & 7, gchunk = lane >> 3;
    const int r2 = w * 16 + grow * 2;      // V-staging rows (r2, r2+1)
    const int c8 = gchunk * 8;             // V-staging col group
    const float scale = 0.125f;

    #pragma unroll
    for (int pass = 0; pass < 2; ++pass) {
        const int qt = pass ? (31 - p) : p;
        // Q fragments (A-layout) straight from global
        ushort8 qf[2];
        const u16* qrow = Q + (size_t)(qt * 64 + w * 16 + lr) * 64;
        qf[0] = *(const ushort8*)(qrow + quad * 8);
        qf[1] = *(const ushort8*)(qrow + 32 + quad * 8);
        f32x4 o_acc[4] = {};
        float m_i[4], l_i[4];
        #pragma unroll
        for (int r = 0; r < 4; ++r) { m_i[r] = -1e30f; l_i[r] = 0.f; }

        // prefetch K tile 0
        #pragma unroll
        for (int r = 0; r < 2; ++r) {
            int rb = w * 2 + r;
            async16(Ks + rb * 512, K + (size_t)(rb * 8 + grow) * 64 + gchunk * 8);
        }

        for (int kt = 0; kt <= qt; ++kt) {
            // V tile -> registers (2 rows x 8 cols per thread)
            const u16* vsrc = V + (size_t)(kt * 64 + r2) * 64 + c8;
            ushort8 v0 = *(const ushort8*)vsrc;
            ushort8 v1 = *(const ushort8*)(vsrc + 64);

            __syncthreads();  // K(kt) async done; prev PV reads of Vts/Ps done

            // S = Q K^T
            f32x4 s[4] = {};
            #pragma unroll
            for (int nt = 0; nt < 4; ++nt)
                #pragma unroll
                for (int kk = 0; kk < 2; ++kk) {
                    ushort8 bb = *(ushort8*)&Ks[(nt * 2 + (lr >> 3)) * 512 +
                                                (kk * 4 + quad) * 64 + (lr & 7) * 8];
                    s[nt] = MFMA16(qf[kk], bb, s[nt]);
                }
            // scale + causal mask on diagonal tile
            if (kt == qt) {
                #pragma unroll
                for (int nt = 0; nt < 4; ++nt)
                    #pragma unroll
                    for (int reg = 0; reg < 4; ++reg) {
                        int qr = w * 16 + quad * 4 + reg;  // tile-local? no: mask is tile-local
                        int kc = nt * 16 + lr;
                        s[nt][reg] = (kc > (quad * 4 + reg) + w * 16 - w * 16 + (w * 16 + quad * 4 + reg) - (w * 16 + quad * 4 + reg) + (w * 16 + quad * 4 + reg)) ? s[nt][reg] : s[nt][reg];
                        // (simplified below)
                        (void)qr; (void)kc;
                    }
                #pragma unroll
                for (int nt = 0; nt < 4; ++nt)
                    #pragma unroll
                    for (int reg = 0; reg < 4; ++reg) {
                        int qr = w * 16 + quad * 4 + reg;
                        int kc = nt * 16 + lr;
                        s[nt][reg] = (kc > qr) ? -1e30f : s[nt][reg] * scale;
                    }
            } else {
                #pragma unroll
                for (int nt = 0; nt < 4; ++nt)
                    #pragma unroll
                    for (int reg = 0; reg < 4; ++reg) s[nt][reg] *= scale;
            }
            // online softmax (rows split across 16 lanes)
            float pr[4][4], alpha[4];
            #pragma unroll
            for (int reg = 0; reg < 4; ++reg) {
                float mx = fmaxf(fmaxf(s[0][reg], s[1][reg]),
                                 fmaxf(s[2][reg], s[3][reg]));
                #pragma unroll
                for (int off = 1; off < 16; off <<= 1)
                    mx = fmaxf(mx, __shfl_xor(mx, off));
                float mnew = fmaxf(m_i[reg], mx);
                alpha[reg] = __expf(m_i[reg] - mnew);
                m_i[reg] = mnew;
                float rs = 0.f;
                #pragma unroll
                for (int nt = 0; nt < 4; ++nt) {
                    float pv = __expf(s[nt][reg] - mnew);
                    pr[nt][reg] = pv;
                    rs += pv;
                }
                #pragma unroll
                for (int off = 1; off < 16; off <<= 1)
                    rs += __shfl_xor(rs, off);
                l_i[reg] = l_i[reg] * alpha[reg] + rs;
            }
            #pragma unroll
            for (int dt = 0; dt < 4; ++dt)
                #pragma unroll
                for (int reg = 0; reg < 4; ++reg) o_acc[dt][reg] *= alpha[reg];

            // write Vts (packed b32, rotated for bank spread) and Ps
            unsigned int pk[8];
            #pragma unroll
            for (int i = 0; i < 8; ++i)
                pk[i] = (unsigned int)v0[i] | ((unsigned int)v1[i] << 16);
            #pragma unroll
            for (int ii = 0; ii < 8; ++ii) {
                int i = (ii + gchunk) & 7;
                *(unsigned int*)&Vts[(c8 + i) * 72 + r2] = pk[i];
            }
            #pragma unroll
            for (int nt = 0; nt < 4; ++nt)
                #pragma unroll
                for (int reg = 0; reg < 4; ++reg)
                    Ps[(w * 16 + quad * 4 + reg) * 72 + nt * 16 + lr] =
                        f2bf(pr[nt][reg]);

            __syncthreads();  // Vts/Ps visible; all waves past QK reads of Ks

            if (kt < qt) {
                #pragma unroll
                for (int r = 0; r < 2; ++r) {
                    int rb = w * 2 + r;
                    async16(Ks + rb * 512,
                            K + (size_t)((kt + 1) * 64 + rb * 8 + grow) * 64 + gchunk * 8);
                }
            }
            // O += P V
            #pragma unroll
            for (int kk = 0; kk < 2; ++kk) {
                ushort8 a = *(ushort8*)&Ps[(w * 16 + lr) * 72 + kk * 32 + quad * 8];
                #pragma unroll
                for (int dt = 0; dt < 4; ++dt) {
                    ushort8 bb = *(ushort8*)&Vts[(dt * 16 + lr) * 72 + kk * 32 + quad * 8];
                    o_acc[dt] = MFMA16(a, bb, o_acc[dt]);
                }
            }
        }

        // epilogue: normalize, write bf16 [b, t, h*64 + d]
        #pragma unroll
        for (int dt = 0; dt < 4; ++dt)
            #pragma unroll
            for (int reg = 0; reg < 4; ++reg) {
                int tq = qt * 64 + w * 16 + quad * 4 + reg;
                float ov = o_acc[dt][reg] / l_i[reg];
                o_ws[((size_t)(b * 2048 + tq) << 10) + h * 64 + dt * 16 + lr] = f2bf(ov);
            }
    }
}

extern "C" void kernel_launch(void* const* d_in, const int* in_sizes, int n_in,
                              void* d_out, int out_size, void* d_ws, size_t ws_size,
                              hipStream_t stream)
{
    const float* x    = (const float*)d_in[0];
    const float* Wqkv = (const float*)d_in[1];
    const float* bqkv = (const float*)d_in[2];
    const float* Wout = (const float*)d_in[3];
    const float* bout = (const float*)d_in[4];
    float* out = (float*)d_out;

    u16* qkvb = (u16*)d_ws;                    // 3 * 8388608 elems (50.3 MB)
    u16* xb   = qkvb + (size_t)3 * 8388608;    // 8388608 elems; aliased as attn_o
    u16* wT   = qkvb + (size_t)4 * 8388608;    // up to 3072*1024 elems (6.3 MB)
    u16* attn_o = xb;

    convert_bf16<<<4096, 256, 0, stream>>>(x, xb);
    transpose_convert<<<dim3(16, 48), 256, 0, stream>>>(Wqkv, wT, 3072, 1024);
    qkv_gemm<<<dim3(64, 24), 256, 0, stream>>>(xb, wT, bqkv, qkvb);
    attn_kernel<<<dim3(16, 16, 4), 256, 0, stream>>>(qkvb, attn_o);
    transpose_convert<<<dim3(16, 16), 256, 0, stream>>>(Wout, wT, 1024, 1024);
    out_gemm<<<dim3(64, 8), 256, 0, stream>>>(attn_o, wT, bout, out);
}